// Round 1
// baseline (1049.128 us; speedup 1.0000x reference)
//
#include <hip/hip_runtime.h>
#include <hip/hip_bf16.h>
#include <stdint.h>

#define B_SZ 1024
#define FIN  4096
#define NMEM 256
#define NQK  16384   // 64 * 256

typedef __attribute__((ext_vector_type(8))) short short8;
typedef __attribute__((ext_vector_type(4))) float floatx4;

__device__ __forceinline__ ushort f2bf(float f) {
    uint32_t u = __float_as_uint(f);
    return (ushort)((u + 0x7fffu + ((u >> 16) & 1u)) >> 16);   // RNE
}
__device__ __forceinline__ float bf2f(ushort u) {
    return __uint_as_float(((uint32_t)u) << 16);
}

// async global->LDS, 16B per lane; lptr must be wave-uniform, HW adds lane*16
__device__ __forceinline__ void gl2lds16(const void* g, void* l) {
    __builtin_amdgcn_global_load_lds(
        (const __attribute__((address_space(1))) void*)g,
        (__attribute__((address_space(3))) void*)l, 16, 0, 0);
}

// ---------------- fp32 -> bf16, 8 elems/thread ----------------
__global__ void cvt_kernel(const float* __restrict__ src, ushort* __restrict__ dst, int n) {
    int i = (blockIdx.x * blockDim.x + threadIdx.x) * 8;
    if (i >= n) return;
    float4 f0 = *(const float4*)(src + i);
    float4 f1 = *(const float4*)(src + i + 4);
    uint4 o;
    o.x = (uint32_t)f2bf(f0.x) | ((uint32_t)f2bf(f0.y) << 16);
    o.y = (uint32_t)f2bf(f0.z) | ((uint32_t)f2bf(f0.w) << 16);
    o.z = (uint32_t)f2bf(f1.x) | ((uint32_t)f2bf(f1.y) << 16);
    o.w = (uint32_t)f2bf(f1.z) | ((uint32_t)f2bf(f1.w) << 16);
    *(uint4*)(dst + i) = o;
}

// ---------------- fp32 [4096 k][NFULL n] -> bf16 [n][k], column chunk at n0 ----------------
// grid: (Nc/64, 4096/64), 256 threads. dst is [Nc][4096] bf16.
__global__ __launch_bounds__(256)
void transT_kernel(const float* __restrict__ src, ushort* __restrict__ dst,
                   int NFULL, int n0) {
    __shared__ float lds[64 * 65];
    const int tid = threadIdx.x;
    const int nc0 = blockIdx.x * 64;   // local n of tile
    const int k0  = blockIdx.y * 64;
    #pragma unroll
    for (int p = 0; p < 4; ++p) {
        int idx = p * 256 + tid;          // 0..1023
        int krow = idx >> 4;              // 0..63
        int c4 = (idx & 15) * 4;          // n-local, x4
        float4 v = *(const float4*)(src + (size_t)(k0 + krow) * NFULL + n0 + nc0 + c4);
        lds[krow * 65 + c4 + 0] = v.x;
        lds[krow * 65 + c4 + 1] = v.y;
        lds[krow * 65 + c4 + 2] = v.z;
        lds[krow * 65 + c4 + 3] = v.w;
    }
    __syncthreads();
    #pragma unroll
    for (int p = 0; p < 2; ++p) {
        int idx = p * 256 + tid;          // 0..511
        int nrow = idx >> 3;              // 0..63
        int c8 = (idx & 7) * 8;           // k-local, x8
        ushort t[8];
        #pragma unroll
        for (int j = 0; j < 8; ++j) t[j] = f2bf(lds[(c8 + j) * 65 + nrow]);
        uint4 o;
        o.x = (uint32_t)t[0] | ((uint32_t)t[1] << 16);
        o.y = (uint32_t)t[2] | ((uint32_t)t[3] << 16);
        o.z = (uint32_t)t[4] | ((uint32_t)t[5] << 16);
        o.w = (uint32_t)t[6] | ((uint32_t)t[7] << 16);
        *(uint4*)(dst + (size_t)(nc0 + nrow) * 4096 + k0 + c8) = o;
    }
}

// ============================================================================
// 256x256 8-phase bf16 GEMM (T2 swizzle + T3/T4 counted vmcnt + T5 setprio).
// A [M][K] bf16, Bt [N][K] bf16 -> C = relu?(A@Bt^T + bias?) bf16, row stride ldc.
// 512 threads = 8 waves (2M x 4N), per-wave 128x64 output, BK=64, dbuf LDS 128 KiB.
// Staging: global_load_lds 16B/lane, source pre-swizzled chunk c = pos ^ (row&7),
// fragment reads XOR the same involution -> conflict-free ds_read_b128.
// Main loop NEVER drains vmcnt to 0: next tile's first half is issued BEFORE the
// boundary s_waitcnt vmcnt(2) + raw s_barrier (counted-vmcnt handshake).
// ============================================================================
template<int RELU, int HASBIAS>
__global__ __launch_bounds__(512, 2)
void gemm256(const ushort* __restrict__ A, const ushort* __restrict__ Bt,
             const float* __restrict__ bias, ushort* __restrict__ C,
             int ldc, int K)
{
    __shared__ __align__(16) ushort As[2][256 * 64];
    __shared__ __align__(16) ushort Bs[2][256 * 64];

    const int tid  = threadIdx.x;
    const int lane = tid & 63;
    const int wave = tid >> 6;       // 0..7
    const int wr   = wave >> 2;      // 0..1 (M half)
    const int wc   = wave & 3;       // 0..3 (N quarter)
    const int m0 = blockIdx.y * 256;
    const int n0 = blockIdx.x * 256;
    const int fr = lane & 15;
    const int fq = lane >> 4;
    const int NT = K >> 6;

    floatx4 acc[8][4] = {};
    short8 a_[4][2];          // A frags for current qm (reloaded per qm)
    short8 b0_[2][2];         // B frags qn=0 (live across phases 0..2)
    short8 b1_[2][2];         // B frags qn=1 (live across phases 1..3)

    // stage one 128-row half of one operand for K-tile at k0 into LDS L.
    // 2 global_load_lds_dwordx4 per wave => vmcnt +2 per call.
    auto stage_half = [&](const ushort* __restrict__ G, int grow0, ushort* L,
                          int h, int k0) {
        #pragma unroll
        for (int i = 0; i < 2; ++i) {
            int id  = i * 512 + tid;         // 0..1023 chunk id within half
            int row = h * 128 + (id >> 3);   // 8 chunks of 16B per 64-elem row
            int pos = id & 7;
            int cc  = pos ^ (row & 7);       // pre-swizzled global source chunk
            gl2lds16(G + (size_t)(grow0 + row) * K + k0 + cc * 8,
                     L + h * 8192 + (i * 512 + wave * 64) * 8);
        }
    };

#define LOAD_A(QM)                                                             \
    {                                                                          \
        _Pragma("unroll")                                                      \
        for (int j = 0; j < 4; ++j) {                                          \
            int r = wr * 128 + ((QM) * 4 + j) * 16 + fr;                       \
            _Pragma("unroll")                                                  \
            for (int ks = 0; ks < 2; ++ks) {                                   \
                int p = (ks * 4 + fq) ^ (r & 7);                               \
                a_[j][ks] = *(const short8*)(&Acur[r * 64 + p * 8]);           \
            }                                                                  \
        }                                                                      \
    }

#define LOAD_B(QN, BB)                                                         \
    {                                                                          \
        _Pragma("unroll")                                                      \
        for (int j = 0; j < 2; ++j) {                                          \
            int r = wc * 64 + ((QN) * 2 + j) * 16 + fr;                        \
            _Pragma("unroll")                                                  \
            for (int ks = 0; ks < 2; ++ks) {                                   \
                int p = (ks * 4 + fq) ^ (r & 7);                               \
                BB[j][ks] = *(const short8*)(&Bcur[r * 64 + p * 8]);           \
            }                                                                  \
        }                                                                      \
    }

#define MFMA_CL(QM, QN, BB)                                                    \
    __builtin_amdgcn_s_setprio(1);                                             \
    _Pragma("unroll")                                                          \
    for (int ks = 0; ks < 2; ++ks)                                             \
        _Pragma("unroll")                                                      \
        for (int j = 0; j < 4; ++j)                                            \
            _Pragma("unroll")                                                  \
            for (int i = 0; i < 2; ++i)                                        \
                acc[(QM) * 4 + j][(QN) * 2 + i] =                              \
                    __builtin_amdgcn_mfma_f32_16x16x32_bf16(                   \
                        a_[j][ks], BB[i][ks],                                  \
                        acc[(QM) * 4 + j][(QN) * 2 + i], 0, 0, 0);             \
    __builtin_amdgcn_s_setprio(0);

    // prologue: stage K-tile 0 into buffer 0 (8 loads/wave outstanding)
    stage_half(A,  m0, &As[0][0], 0, 0);
    stage_half(A,  m0, &As[0][0], 1, 0);
    stage_half(Bt, n0, &Bs[0][0], 0, 0);
    stage_half(Bt, n0, &Bs[0][0], 1, 0);

    for (int kt = 0; kt < NT - 1; ++kt) {
        const int cur = kt & 1;
        const ushort* Acur = &As[cur][0];
        const ushort* Bcur = &Bs[cur][0];
        ushort* An = &As[cur ^ 1][0];
        ushort* Bn = &Bs[cur ^ 1][0];
        const int k0n = (kt + 1) << 6;

        // ---- phase 0 (tile boundary, counted vmcnt: 2 loads stay in flight) ----
        stage_half(A, m0, An, 0, k0n);
        asm volatile("s_waitcnt vmcnt(2)" ::: "memory");
        __builtin_amdgcn_s_barrier();
        __builtin_amdgcn_sched_barrier(0);
        LOAD_A(0);
        LOAD_B(0, b0_);
        asm volatile("s_waitcnt lgkmcnt(0)" ::: "memory");
        __builtin_amdgcn_sched_barrier(0);
        MFMA_CL(0, 0, b0_);
        __builtin_amdgcn_s_barrier();

        // ---- phase 1 ----
        LOAD_B(1, b1_);
        stage_half(A, m0, An, 1, k0n);
        __builtin_amdgcn_s_barrier();
        asm volatile("s_waitcnt lgkmcnt(0)" ::: "memory");
        __builtin_amdgcn_sched_barrier(0);
        MFMA_CL(0, 1, b1_);
        __builtin_amdgcn_s_barrier();

        // ---- phase 2 ----
        LOAD_A(1);
        stage_half(Bt, n0, Bn, 0, k0n);
        __builtin_amdgcn_s_barrier();
        asm volatile("s_waitcnt lgkmcnt(0)" ::: "memory");
        __builtin_amdgcn_sched_barrier(0);
        MFMA_CL(1, 0, b0_);
        __builtin_amdgcn_s_barrier();

        // ---- phase 3 (no ds_reads: all frags already live) ----
        stage_half(Bt, n0, Bn, 1, k0n);
        __builtin_amdgcn_s_barrier();
        MFMA_CL(1, 1, b1_);
        __builtin_amdgcn_s_barrier();
    }

    // ---- tail K-tile (no staging; full drain is cheap once) ----
    {
        const ushort* Acur = &As[(NT - 1) & 1][0];
        const ushort* Bcur = &Bs[(NT - 1) & 1][0];
        asm volatile("s_waitcnt vmcnt(0)" ::: "memory");
        __builtin_amdgcn_s_barrier();
        __builtin_amdgcn_sched_barrier(0);
        LOAD_A(0);
        LOAD_B(0, b0_);
        LOAD_B(1, b1_);
        MFMA_CL(0, 0, b0_);
        MFMA_CL(0, 1, b1_);
        LOAD_A(1);
        MFMA_CL(1, 0, b0_);
        MFMA_CL(1, 1, b1_);
    }

    // epilogue: C/D layout col=lane&15, row=fq*4+reg
    #pragma unroll
    for (int mi = 0; mi < 8; ++mi) {
        #pragma unroll
        for (int ni = 0; ni < 4; ++ni) {
            #pragma unroll
            for (int r = 0; r < 4; ++r) {
                int gm = m0 + wr * 128 + mi * 16 + fq * 4 + r;
                int gn = n0 + wc * 64 + ni * 16 + fr;
                float val = acc[mi][ni][r];
                if (HASBIAS) val += bias[gn];
                if (RELU)    val = fmaxf(val, 0.0f);
                C[(size_t)gm * ldc + gn] = f2bf(val);
            }
        }
    }
#undef LOAD_A
#undef LOAD_B
#undef MFMA_CL
}

// ---------------- bf16 A [M][K] x bf16 B^T [N][K] MFMA GEMM, m97-style ----------------
// (kept for the final 1024x4096x4096 GEMM, where a 256^2 grid would be only 64 blocks)
template<int RELU, int HASBIAS, int RESID, int OUTBF>
__global__ __launch_bounds__(256)
void gemm_bf(const ushort* __restrict__ A, const ushort* __restrict__ Bt,
             const float* __restrict__ bias, const float* __restrict__ resid,
             void* __restrict__ Cout, int ldc, int M, int K)
{
    __shared__ __align__(16) ushort As[128 * 64];
    __shared__ __align__(16) ushort Bs[128 * 64];

    const int tid  = threadIdx.x;
    const int lane = tid & 63;
    const int wave = tid >> 6;
    const int wm = (wave >> 1) * 64;
    const int wn = (wave & 1) * 64;
    const int m0 = blockIdx.y * 128;
    const int n0 = blockIdx.x * 128;

    const int fr = lane & 15;
    const int fq = lane >> 4;

    floatx4 acc[4][4] = {};

    for (int k0 = 0; k0 < K; k0 += 64) {
        __syncthreads();
        #pragma unroll
        for (int i = 0; i < 4; ++i) {
            int id = i * 256 + wave * 64 + lane;
            int row = id >> 3, pos = id & 7;
            int c = pos ^ (row & 7);
            gl2lds16(A + (size_t)(m0 + row) * K + k0 + c * 8,
                     &As[(i * 256 + wave * 64) * 8]);
        }
        #pragma unroll
        for (int i = 0; i < 4; ++i) {
            int id = i * 256 + wave * 64 + lane;
            int row = id >> 3, pos = id & 7;
            int c = pos ^ (row & 7);
            gl2lds16(Bt + (size_t)(n0 + row) * K + k0 + c * 8,
                     &Bs[(i * 256 + wave * 64) * 8]);
        }
        __syncthreads();

        #pragma unroll
        for (int ks = 0; ks < 2; ++ks) {
            short8 a[4], b[4];
            #pragma unroll
            for (int i = 0; i < 4; ++i) {
                int row = wm + i * 16 + fr;
                int p = (ks * 4 + fq) ^ (row & 7);
                a[i] = *(const short8*)(&As[row * 64 + p * 8]);
            }
            #pragma unroll
            for (int i = 0; i < 4; ++i) {
                int row = wn + i * 16 + fr;
                int p = (ks * 4 + fq) ^ (row & 7);
                b[i] = *(const short8*)(&Bs[row * 64 + p * 8]);
            }
            #pragma unroll
            for (int mi = 0; mi < 4; ++mi)
                #pragma unroll
                for (int ni = 0; ni < 4; ++ni)
                    acc[mi][ni] = __builtin_amdgcn_mfma_f32_16x16x32_bf16(
                        a[mi], b[ni], acc[mi][ni], 0, 0, 0);
        }
    }

    #pragma unroll
    for (int mi = 0; mi < 4; ++mi) {
        #pragma unroll
        for (int ni = 0; ni < 4; ++ni) {
            #pragma unroll
            for (int r = 0; r < 4; ++r) {
                int gm = m0 + wm + mi * 16 + fq * 4 + r;
                int gn = n0 + wn + ni * 16 + fr;
                float val = acc[mi][ni][r];
                if (HASBIAS) val += bias[gn];
                if (RELU)    val = fmaxf(val, 0.0f);
                if (RESID)   val += resid[(size_t)gm * ldc + gn];
                if (OUTBF) ((ushort*)Cout)[(size_t)gm * ldc + gn] = f2bf(val);
                else       ((float*)Cout)[(size_t)gm * ldc + gn] = val;
            }
        }
    }
}

// ---------------- bf16-A x fp32-B GEMM (convert-in-LDS path, round-1 proven) ----------------
#define BM 128
#define BN 128
#define BKK 64
#define LDA 72
#define LDB 72

template<int RELU, int HASBIAS, int RESID, int OUTBF>
__global__ __launch_bounds__(256)
void gemm_k(const ushort* __restrict__ A, const float* __restrict__ B,
            const float* __restrict__ bias, const float* __restrict__ resid,
            void* __restrict__ Cout, int M, int N, int K)
{
    __shared__ ushort As[BM * LDA];
    __shared__ ushort Bs[BN * LDB];

    const int tid  = threadIdx.x;
    const int lane = tid & 63;
    const int wave = tid >> 6;
    const int wm = (wave >> 1) * 64;
    const int wn = (wave & 1) * 64;
    const int m0 = blockIdx.y * BM;
    const int n0 = blockIdx.x * BN;

    const int fr = lane & 15;
    const int fq = lane >> 4;

    floatx4 acc[4][4] = {};

    for (int k0 = 0; k0 < K; k0 += BKK) {
        __syncthreads();
        #pragma unroll
        for (int c = 0; c < 4; ++c) {
            int idx = c * 256 + tid;
            int row = idx >> 3;
            int off = idx & 7;
            *(uint4*)(&As[row * LDA + off * 8]) =
                *(const uint4*)(A + (size_t)(m0 + row) * K + k0 + off * 8);
        }
        #pragma unroll
        for (int p = 0; p < 8; ++p) {
            int idx = p * 256 + tid;
            int nn = idx & 127;
            int kg = idx >> 7;
            const float* bp = B + (size_t)(k0 + kg * 4) * N + n0 + nn;
            float f0 = bp[0];
            float f1 = bp[N];
            float f2 = bp[2 * (size_t)N];
            float f3 = bp[3 * (size_t)N];
            ushort4 w;
            w.x = f2bf(f0); w.y = f2bf(f1); w.z = f2bf(f2); w.w = f2bf(f3);
            *(ushort4*)(&Bs[nn * LDB + kg * 4]) = w;
        }
        __syncthreads();

        #pragma unroll
        for (int ks = 0; ks < 2; ++ks) {
            short8 a[4], b[4];
            #pragma unroll
            for (int i = 0; i < 4; ++i)
                a[i] = *(const short8*)(&As[(wm + i * 16 + fr) * LDA + ks * 32 + fq * 8]);
            #pragma unroll
            for (int i = 0; i < 4; ++i)
                b[i] = *(const short8*)(&Bs[(wn + i * 16 + fr) * LDB + ks * 32 + fq * 8]);
            #pragma unroll
            for (int mi = 0; mi < 4; ++mi)
                #pragma unroll
                for (int ni = 0; ni < 4; ++ni)
                    acc[mi][ni] = __builtin_amdgcn_mfma_f32_16x16x32_bf16(
                        a[mi], b[ni], acc[mi][ni], 0, 0, 0);
        }
    }

    #pragma unroll
    for (int mi = 0; mi < 4; ++mi) {
        #pragma unroll
        for (int ni = 0; ni < 4; ++ni) {
            #pragma unroll
            for (int r = 0; r < 4; ++r) {
                int gm = m0 + wm + mi * 16 + fq * 4 + r;
                int gn = n0 + wn + ni * 16 + fr;
                float val = acc[mi][ni][r];
                if (HASBIAS) val += bias[gn];
                if (RELU)    val = fmaxf(val, 0.0f);
                if (RESID)   val += resid[(size_t)gm * N + gn];
                if (OUTBF) ((ushort*)Cout)[(size_t)gm * N + gn] = f2bf(val);
                else       ((float*)Cout)[(size_t)gm * N + gn] = val;
            }
        }
    }
}

// ---------------- qbar[b,s] = (1/(256*8)) * sum_m XQr[b, m*64+s] ----------------
__global__ void qbar_kernel(const ushort* __restrict__ XQr, float* __restrict__ qbar) {
    int b = blockIdx.x;
    int s = threadIdx.x;  // 64 threads = 1 wave
    const ushort* p = XQr + (size_t)b * NQK + s;
    float sum = 0.0f;
    #pragma unroll 4
    for (int m = 0; m < NMEM; ++m) sum += bf2f(p[m * 64]);
    qbar[b * 64 + s] = sum * (1.0f / (NMEM * 8.0f));
}

// ---------------- s_pooled[b,n] = sum_s XKr[b, n*64+s] * qbar[b,s] -> bf16 ----------------
__global__ void spool_kernel(const ushort* __restrict__ XKr, const float* __restrict__ qbar,
                             ushort* __restrict__ spb) {
    int b = blockIdx.x;
    int n = threadIdx.x;  // 256 threads
    __shared__ float q[64];
    if (threadIdx.x < 64) q[threadIdx.x] = qbar[b * 64 + threadIdx.x];
    __syncthreads();
    const ushort* p = XKr + (size_t)b * NQK + n * 64;
    float sum = 0.0f;
    #pragma unroll
    for (int s = 0; s < 64; s += 4) {
        ushort4 u = *(const ushort4*)(p + s);
        sum += bf2f(u.x) * q[s] + bf2f(u.y) * q[s + 1]
             + bf2f(u.z) * q[s + 2] + bf2f(u.w) * q[s + 3];
    }
    spb[b * 256 + n] = f2bf(sum);
}

extern "C" void kernel_launch(void* const* d_in, const int* in_sizes, int n_in,
                              void* d_out, int out_size, void* d_ws, size_t ws_size,
                              hipStream_t stream) {
    const float* x  = (const float*)d_in[0];
    const float* Wq = (const float*)d_in[1];
    const float* bq = (const float*)d_in[2];
    const float* Wk = (const float*)d_in[3];
    const float* bk = (const float*)d_in[4];
    const float* v  = (const float*)d_in[5];
    const float* Wl = (const float*)d_in[6];
    const float* bl = (const float*)d_in[7];
    float* out = (float*)d_out;

    const size_t MB = 1ull << 20;
    char* ws = (char*)d_ws;
    ushort* xb   = (ushort*)(ws + 0);        //  8 MB  x bf16 [1024][4096]
    ushort* XQr  = (ushort*)(ws + 8 * MB);   // 32 MB  relu(x@Wq+bq) bf16 [1024][16384]
    ushort* XKr  = (ushort*)(ws + 40 * MB);  // 32 MB
    float*  qbar = (float*)(ws + 72 * MB);   // 256 KB [1024][64]
    ushort* spb  = (ushort*)(ws + 73 * MB);  // 512 KB s_pooled bf16 [1024][256]
    ushort* p2b  = (ushort*)(ws + 74 * MB);  //  8 MB  (spb@v) bf16 [1024][4096]
    ushort* WT   = (ushort*)(ws + 82 * MB);  // 128 MB transposed bf16 weight [16384][4096]

    // x -> bf16
    cvt_kernel<<<dim3((B_SZ * FIN) / 8 / 256), 256, 0, stream>>>(x, xb, B_SZ * FIN);

    // Q projection: full-N transpose (128 MB WT), one 256^2 8-phase GEMM (grid 64x4 = 256 blocks)
    transT_kernel<<<dim3(NQK / 64, FIN / 64), 256, 0, stream>>>(Wq, WT, NQK, 0);
    gemm256<1, 1><<<dim3(NQK / 256, B_SZ / 256), 512, 0, stream>>>(
        xb, WT, bq, XQr, NQK, FIN);
    qbar_kernel<<<dim3(B_SZ), 64, 0, stream>>>(XQr, qbar);

    // K projection
    transT_kernel<<<dim3(NQK / 64, FIN / 64), 256, 0, stream>>>(Wk, WT, NQK, 0);
    gemm256<1, 1><<<dim3(NQK / 256, B_SZ / 256), 512, 0, stream>>>(
        xb, WT, bk, XKr, NQK, FIN);
    spool_kernel<<<dim3(B_SZ), 256, 0, stream>>>(XKr, qbar, spb);

    // p2 = spb @ v  (fp32-B path, K=256), bf16 out
    gemm_k<0, 0, 0, 1><<<dim3(FIN / BN, B_SZ / BM), 256, 0, stream>>>(
        spb, v, nullptr, nullptr, p2b, B_SZ, FIN, NMEM);

    // WlT (32 MB into WT buffer), then out = x + p2 @ Wl + bl
    transT_kernel<<<dim3(FIN / 64, FIN / 64), 256, 0, stream>>>(Wl, WT, FIN, 0);
    gemm_bf<0, 1, 1, 0><<<dim3(FIN / 128, B_SZ / 128), 256, 0, stream>>>(
        p2b, WT, bl, x, out, FIN, B_SZ, FIN);
}

// Round 2
// 1008.804 us; speedup vs baseline: 1.0400x; 1.0400x over previous
//
#include <hip/hip_runtime.h>
#include <hip/hip_bf16.h>
#include <stdint.h>

#define B_SZ 1024
#define FIN  4096
#define NMEM 256
#define NQK  16384   // 64 * 256

typedef __attribute__((ext_vector_type(8))) short short8;
typedef __attribute__((ext_vector_type(4))) float floatx4;

__device__ __forceinline__ ushort f2bf(float f) {
    uint32_t u = __float_as_uint(f);
    return (ushort)((u + 0x7fffu + ((u >> 16) & 1u)) >> 16);   // RNE
}
__device__ __forceinline__ float bf2f(ushort u) {
    return __uint_as_float(((uint32_t)u) << 16);
}

// async global->LDS, 16B per lane; lptr must be wave-uniform, HW adds lane*16
__device__ __forceinline__ void gl2lds16(const void* g, void* l) {
    __builtin_amdgcn_global_load_lds(
        (const __attribute__((address_space(1))) void*)g,
        (__attribute__((address_space(3))) void*)l, 16, 0, 0);
}

// ---------------- fp32 -> bf16, 8 elems/thread ----------------
__global__ void cvt_kernel(const float* __restrict__ src, ushort* __restrict__ dst, int n) {
    int i = (blockIdx.x * blockDim.x + threadIdx.x) * 8;
    if (i >= n) return;
    float4 f0 = *(const float4*)(src + i);
    float4 f1 = *(const float4*)(src + i + 4);
    uint4 o;
    o.x = (uint32_t)f2bf(f0.x) | ((uint32_t)f2bf(f0.y) << 16);
    o.y = (uint32_t)f2bf(f0.z) | ((uint32_t)f2bf(f0.w) << 16);
    o.z = (uint32_t)f2bf(f1.x) | ((uint32_t)f2bf(f1.y) << 16);
    o.w = (uint32_t)f2bf(f1.z) | ((uint32_t)f2bf(f1.w) << 16);
    *(uint4*)(dst + i) = o;
}

// ---------------- fp32 [4096 k][NFULL n] -> bf16 [n][k], column chunk at n0 ----------------
__global__ __launch_bounds__(256)
void transT_kernel(const float* __restrict__ src, ushort* __restrict__ dst,
                   int NFULL, int n0) {
    __shared__ float lds[64 * 65];
    const int tid = threadIdx.x;
    const int nc0 = blockIdx.x * 64;   // local n of tile
    const int k0  = blockIdx.y * 64;
    #pragma unroll
    for (int p = 0; p < 4; ++p) {
        int idx = p * 256 + tid;          // 0..1023
        int krow = idx >> 4;              // 0..63
        int c4 = (idx & 15) * 4;          // n-local, x4
        float4 v = *(const float4*)(src + (size_t)(k0 + krow) * NFULL + n0 + nc0 + c4);
        lds[krow * 65 + c4 + 0] = v.x;
        lds[krow * 65 + c4 + 1] = v.y;
        lds[krow * 65 + c4 + 2] = v.z;
        lds[krow * 65 + c4 + 3] = v.w;
    }
    __syncthreads();
    #pragma unroll
    for (int p = 0; p < 2; ++p) {
        int idx = p * 256 + tid;          // 0..511
        int nrow = idx >> 3;              // 0..63
        int c8 = (idx & 7) * 8;           // k-local, x8
        ushort t[8];
        #pragma unroll
        for (int j = 0; j < 8; ++j) t[j] = f2bf(lds[(c8 + j) * 65 + nrow]);
        uint4 o;
        o.x = (uint32_t)t[0] | ((uint32_t)t[1] << 16);
        o.y = (uint32_t)t[2] | ((uint32_t)t[3] << 16);
        o.z = (uint32_t)t[4] | ((uint32_t)t[5] << 16);
        o.w = (uint32_t)t[6] | ((uint32_t)t[7] << 16);
        *(uint4*)(dst + (size_t)(nc0 + nrow) * 4096 + k0 + c8) = o;
    }
}

// ============================================================================
// 256x256 4-phase bf16 GEMM, DEEP counted-vmcnt pipeline (round-2 schedule).
//
// Round-1 failure: tile halves were staged ph0..ph3 and waited at the very next
// boundary -> youngest load had ~1 barrier of cover -> ~600cyc stall/tile
// (m218 "drain" regime, 827 TF). Fix: tile T+1's halves are staged at slots
// [(T-1).P3, T.P0, T.P1, T.P2]; T.P3 stages tile T+2's FIRST half and then
// waits vmcnt(2) (in flight = only that just-issued half). The youngest load
// the wait depends on (B-h1(T+1), staged T.P2) has a full MFMA phase of cover;
// older halves have 2-4 phases.
//
// WAR safety (why staging this early is legal): every region of buf[p] is
// ds_read-drained by each wave before its P2 lgkmcnt(0), and ALL waves are past
// that point at P2's closing barrier. Slots from P3 onward may overwrite the
// same-parity buffer. Stage slots used here all sit at/after that barrier.
// vmcnt math: 2 loads/wave per half; at T.P3 outstanding = halves staged at
// T.P0,P1,P2,P3 = 8 loads; vmcnt(2) drains the three T+1 halves (+ anything
// older, incl. A-h0(T+1) from (T-1).P3), leaving A-h0(T+2) in flight.
// ============================================================================
template<int RELU, int HASBIAS>
__global__ __launch_bounds__(512, 2)
void gemm256(const ushort* __restrict__ A, const ushort* __restrict__ Bt,
             const float* __restrict__ bias, ushort* __restrict__ C,
             int ldc, int K)
{
    __shared__ __align__(16) ushort As[2][256 * 64];
    __shared__ __align__(16) ushort Bs[2][256 * 64];

    const int tid  = threadIdx.x;
    const int lane = tid & 63;
    const int wave = tid >> 6;       // 0..7
    const int wr   = wave >> 2;      // 0..1 (M half)
    const int wc   = wave & 3;       // 0..3 (N quarter)
    const int m0 = blockIdx.y * 256;
    const int n0 = blockIdx.x * 256;
    const int fr = lane & 15;
    const int fq = lane >> 4;
    const int NT = K >> 6;           // 64 for K=4096 (NT >= 2 assumed)

    floatx4 acc[8][4] = {};
    short8 a_[4][2];          // A frags for current qm (reloaded at P0 and P2)
    short8 b0_[2][2];         // B frags qn=0 (read P0, used P0+P2)
    short8 b1_[2][2];         // B frags qn=1 (read P1, used P1+P3)

    // stage one 128-row half of one operand for K-tile at k0 into LDS L.
    // exactly 2 global_load_lds_dwordx4 per wave => vmcnt +2 per call.
    auto stage_half = [&](const ushort* __restrict__ G, int grow0, ushort* L,
                          int h, int k0) {
        #pragma unroll
        for (int i = 0; i < 2; ++i) {
            int id  = i * 512 + tid;         // 0..1023 chunk id within half
            int row = h * 128 + (id >> 3);   // 8 chunks of 16B per 64-elem row
            int pos = id & 7;
            int cc  = pos ^ (row & 7);       // pre-swizzled global source chunk
            gl2lds16(G + (size_t)(grow0 + row) * K + k0 + cc * 8,
                     L + h * 8192 + (i * 512 + wave * 64) * 8);
        }
    };

#define LOAD_A(QM)                                                             \
    {                                                                          \
        _Pragma("unroll")                                                      \
        for (int j = 0; j < 4; ++j) {                                          \
            int r = wr * 128 + ((QM) * 4 + j) * 16 + fr;                       \
            _Pragma("unroll")                                                  \
            for (int ks = 0; ks < 2; ++ks) {                                   \
                int p = (ks * 4 + fq) ^ (r & 7);                               \
                a_[j][ks] = *(const short8*)(&Acur[r * 64 + p * 8]);           \
            }                                                                  \
        }                                                                      \
    }

#define LOAD_B(QN, BB)                                                         \
    {                                                                          \
        _Pragma("unroll")                                                      \
        for (int j = 0; j < 2; ++j) {                                          \
            int r = wc * 64 + ((QN) * 2 + j) * 16 + fr;                        \
            _Pragma("unroll")                                                  \
            for (int ks = 0; ks < 2; ++ks) {                                   \
                int p = (ks * 4 + fq) ^ (r & 7);                               \
                BB[j][ks] = *(const short8*)(&Bcur[r * 64 + p * 8]);           \
            }                                                                  \
        }                                                                      \
    }

#define MFMA_CL(QM, QN, BB)                                                    \
    __builtin_amdgcn_s_setprio(1);                                             \
    _Pragma("unroll")                                                          \
    for (int ks = 0; ks < 2; ++ks)                                             \
        _Pragma("unroll")                                                      \
        for (int j = 0; j < 4; ++j)                                            \
            _Pragma("unroll")                                                  \
            for (int i = 0; i < 2; ++i)                                        \
                acc[(QM) * 4 + j][(QN) * 2 + i] =                              \
                    __builtin_amdgcn_mfma_f32_16x16x32_bf16(                   \
                        a_[j][ks], BB[i][ks],                                  \
                        acc[(QM) * 4 + j][(QN) * 2 + i], 0, 0, 0);             \
    __builtin_amdgcn_s_setprio(0);

    // ---- prologue: tile 0 fully + tile 1's first half ((T-1).P3 slot for T=1)
    stage_half(A,  m0, &As[0][0], 0, 0);
    stage_half(A,  m0, &As[0][0], 1, 0);
    stage_half(Bt, n0, &Bs[0][0], 0, 0);
    stage_half(Bt, n0, &Bs[0][0], 1, 0);
    stage_half(A,  m0, &As[1][0], 0, 64);          // A-h0(T1)
    asm volatile("s_waitcnt vmcnt(2)" ::: "memory"); // tile 0 resident
    __builtin_amdgcn_s_barrier();

    for (int kt = 0; kt < NT; ++kt) {
        const int cur = kt & 1;
        const ushort* Acur = &As[cur][0];
        const ushort* Bcur = &Bs[cur][0];
        ushort* Abuf = &As[cur][0];
        ushort* An = &As[cur ^ 1][0];
        ushort* Bn = &Bs[cur ^ 1][0];
        const int k1 = (kt + 1) << 6;
        const int k2 = (kt + 2) << 6;
        const bool stg1 = kt + 1 < NT;   // finish staging tile kt+1
        const bool stg2 = kt + 2 < NT;   // start staging tile kt+2

        // ---- P0: reads for (qm0,*) quadrant row + B qn0; stage A-h1(T+1) ----
        // (reads come right after the release barrier; their ~200cyc latency is
        //  the one exposed read burst per tile)
        LOAD_A(0);
        LOAD_B(0, b0_);
        if (stg1) stage_half(A, m0, An, 1, k1);
        asm volatile("s_waitcnt lgkmcnt(0)" ::: "memory");
        __builtin_amdgcn_sched_barrier(0);
        MFMA_CL(0, 0, b0_);
        __builtin_amdgcn_s_barrier();

        // ---- P1: read B qn1; stage B-h0(T+1) ----
        LOAD_B(1, b1_);
        if (stg1) stage_half(Bt, n0, Bn, 0, k1);
        __builtin_amdgcn_s_barrier();
        asm volatile("s_waitcnt lgkmcnt(0)" ::: "memory");
        __builtin_amdgcn_sched_barrier(0);
        MFMA_CL(0, 1, b1_);
        __builtin_amdgcn_s_barrier();

        // ---- P2: read A qm1; stage B-h1(T+1) ----
        LOAD_A(1);
        if (stg1) stage_half(Bt, n0, Bn, 1, k1);
        __builtin_amdgcn_s_barrier();
        asm volatile("s_waitcnt lgkmcnt(0)" ::: "memory");
        __builtin_amdgcn_sched_barrier(0);
        MFMA_CL(1, 0, b0_);
        __builtin_amdgcn_s_barrier();
        // ^ this barrier proves all waves drained ALL reads of buf[cur] -> the
        //   same-parity buffer regions become writable (P3 stage + next-iter slots)

        // ---- P3: stage A-h0(T+2) into same-parity buffer, MFMA, counted wait ----
        if (stg2) stage_half(A, m0, Abuf, 0, k2);
        MFMA_CL(1, 1, b1_);
        if (kt < NT - 1) {
            if (stg2) { asm volatile("s_waitcnt vmcnt(2)" ::: "memory"); }
            else      { asm volatile("s_waitcnt vmcnt(0)" ::: "memory"); }
            __builtin_amdgcn_s_barrier();   // release buf[cur^1] for tile kt+1
        }
    }

    // epilogue: C/D layout col=lane&15, row=fq*4+reg
    #pragma unroll
    for (int mi = 0; mi < 8; ++mi) {
        #pragma unroll
        for (int ni = 0; ni < 4; ++ni) {
            #pragma unroll
            for (int r = 0; r < 4; ++r) {
                int gm = m0 + wr * 128 + mi * 16 + fq * 4 + r;
                int gn = n0 + wc * 64 + ni * 16 + fr;
                float val = acc[mi][ni][r];
                if (HASBIAS) val += bias[gn];
                if (RELU)    val = fmaxf(val, 0.0f);
                C[(size_t)gm * ldc + gn] = f2bf(val);
            }
        }
    }
#undef LOAD_A
#undef LOAD_B
#undef MFMA_CL
}

// ---------------- bf16 A [M][K] x bf16 B^T [N][K] MFMA GEMM, m97-style ----------------
// (kept for the final 1024x4096x4096 GEMM: 32x8=256 blocks at 128^2, ~3 blocks/CU)
template<int RELU, int HASBIAS, int RESID, int OUTBF>
__global__ __launch_bounds__(256)
void gemm_bf(const ushort* __restrict__ A, const ushort* __restrict__ Bt,
             const float* __restrict__ bias, const float* __restrict__ resid,
             void* __restrict__ Cout, int ldc, int M, int K)
{
    __shared__ __align__(16) ushort As[128 * 64];
    __shared__ __align__(16) ushort Bs[128 * 64];

    const int tid  = threadIdx.x;
    const int lane = tid & 63;
    const int wave = tid >> 6;
    const int wm = (wave >> 1) * 64;
    const int wn = (wave & 1) * 64;
    const int m0 = blockIdx.y * 128;
    const int n0 = blockIdx.x * 128;

    const int fr = lane & 15;
    const int fq = lane >> 4;

    floatx4 acc[4][4] = {};

    for (int k0 = 0; k0 < K; k0 += 64) {
        __syncthreads();
        #pragma unroll
        for (int i = 0; i < 4; ++i) {
            int id = i * 256 + wave * 64 + lane;
            int row = id >> 3, pos = id & 7;
            int c = pos ^ (row & 7);
            gl2lds16(A + (size_t)(m0 + row) * K + k0 + c * 8,
                     &As[(i * 256 + wave * 64) * 8]);
        }
        #pragma unroll
        for (int i = 0; i < 4; ++i) {
            int id = i * 256 + wave * 64 + lane;
            int row = id >> 3, pos = id & 7;
            int c = pos ^ (row & 7);
            gl2lds16(Bt + (size_t)(n0 + row) * K + k0 + c * 8,
                     &Bs[(i * 256 + wave * 64) * 8]);
        }
        __syncthreads();

        #pragma unroll
        for (int ks = 0; ks < 2; ++ks) {
            short8 a[4], b[4];
            #pragma unroll
            for (int i = 0; i < 4; ++i) {
                int row = wm + i * 16 + fr;
                int p = (ks * 4 + fq) ^ (row & 7);
                a[i] = *(const short8*)(&As[row * 64 + p * 8]);
            }
            #pragma unroll
            for (int i = 0; i < 4; ++i) {
                int row = wn + i * 16 + fr;
                int p = (ks * 4 + fq) ^ (row & 7);
                b[i] = *(const short8*)(&Bs[row * 64 + p * 8]);
            }
            #pragma unroll
            for (int mi = 0; mi < 4; ++mi)
                #pragma unroll
                for (int ni = 0; ni < 4; ++ni)
                    acc[mi][ni] = __builtin_amdgcn_mfma_f32_16x16x32_bf16(
                        a[mi], b[ni], acc[mi][ni], 0, 0, 0);
        }
    }

    #pragma unroll
    for (int mi = 0; mi < 4; ++mi) {
        #pragma unroll
        for (int ni = 0; ni < 4; ++ni) {
            #pragma unroll
            for (int r = 0; r < 4; ++r) {
                int gm = m0 + wm + mi * 16 + fq * 4 + r;
                int gn = n0 + wn + ni * 16 + fr;
                float val = acc[mi][ni][r];
                if (HASBIAS) val += bias[gn];
                if (RELU)    val = fmaxf(val, 0.0f);
                if (RESID)   val += resid[(size_t)gm * ldc + gn];
                if (OUTBF) ((ushort*)Cout)[(size_t)gm * ldc + gn] = f2bf(val);
                else       ((float*)Cout)[(size_t)gm * ldc + gn] = val;
            }
        }
    }
}

// ---------------- bf16-A x fp32-B GEMM (convert-in-LDS path, round-1 proven) ----------------
#define BM 128
#define BN 128
#define BKK 64
#define LDA 72
#define LDB 72

template<int RELU, int HASBIAS, int RESID, int OUTBF>
__global__ __launch_bounds__(256)
void gemm_k(const ushort* __restrict__ A, const float* __restrict__ B,
            const float* __restrict__ bias, const float* __restrict__ resid,
            void* __restrict__ Cout, int M, int N, int K)
{
    __shared__ ushort As[BM * LDA];
    __shared__ ushort Bs[BN * LDB];

    const int tid  = threadIdx.x;
    const int lane = tid & 63;
    const int wave = tid >> 6;
    const int wm = (wave >> 1) * 64;
    const int wn = (wave & 1) * 64;
    const int m0 = blockIdx.y * BM;
    const int n0 = blockIdx.x * BN;

    const int fr = lane & 15;
    const int fq = lane >> 4;

    floatx4 acc[4][4] = {};

    for (int k0 = 0; k0 < K; k0 += BKK) {
        __syncthreads();
        #pragma unroll
        for (int c = 0; c < 4; ++c) {
            int idx = c * 256 + tid;
            int row = idx >> 3;
            int off = idx & 7;
            *(uint4*)(&As[row * LDA + off * 8]) =
                *(const uint4*)(A + (size_t)(m0 + row) * K + k0 + off * 8);
        }
        #pragma unroll
        for (int p = 0; p < 8; ++p) {
            int idx = p * 256 + tid;
            int nn = idx & 127;
            int kg = idx >> 7;
            const float* bp = B + (size_t)(k0 + kg * 4) * N + n0 + nn;
            float f0 = bp[0];
            float f1 = bp[N];
            float f2 = bp[2 * (size_t)N];
            float f3 = bp[3 * (size_t)N];
            ushort4 w;
            w.x = f2bf(f0); w.y = f2bf(f1); w.z = f2bf(f2); w.w = f2bf(f3);
            *(ushort4*)(&Bs[nn * LDB + kg * 4]) = w;
        }
        __syncthreads();

        #pragma unroll
        for (int ks = 0; ks < 2; ++ks) {
            short8 a[4], b[4];
            #pragma unroll
            for (int i = 0; i < 4; ++i)
                a[i] = *(const short8*)(&As[(wm + i * 16 + fr) * LDA + ks * 32 + fq * 8]);
            #pragma unroll
            for (int i = 0; i < 4; ++i)
                b[i] = *(const short8*)(&Bs[(wn + i * 16 + fr) * LDB + ks * 32 + fq * 8]);
            #pragma unroll
            for (int mi = 0; mi < 4; ++mi)
                #pragma unroll
                for (int ni = 0; ni < 4; ++ni)
                    acc[mi][ni] = __builtin_amdgcn_mfma_f32_16x16x32_bf16(
                        a[mi], b[ni], acc[mi][ni], 0, 0, 0);
        }
    }

    #pragma unroll
    for (int mi = 0; mi < 4; ++mi) {
        #pragma unroll
        for (int ni = 0; ni < 4; ++ni) {
            #pragma unroll
            for (int r = 0; r < 4; ++r) {
                int gm = m0 + wm + mi * 16 + fq * 4 + r;
                int gn = n0 + wn + ni * 16 + fr;
                float val = acc[mi][ni][r];
                if (HASBIAS) val += bias[gn];
                if (RELU)    val = fmaxf(val, 0.0f);
                if (RESID)   val += resid[(size_t)gm * N + gn];
                if (OUTBF) ((ushort*)Cout)[(size_t)gm * N + gn] = f2bf(val);
                else       ((float*)Cout)[(size_t)gm * N + gn] = val;
            }
        }
    }
}

// ---------------- qbar[b,s] = (1/(256*8)) * sum_m XQr[b, m*64+s] ----------------
__global__ void qbar_kernel(const ushort* __restrict__ XQr, float* __restrict__ qbar) {
    int b = blockIdx.x;
    int s = threadIdx.x;  // 64 threads = 1 wave
    const ushort* p = XQr + (size_t)b * NQK + s;
    float sum = 0.0f;
    #pragma unroll 4
    for (int m = 0; m < NMEM; ++m) sum += bf2f(p[m * 64]);
    qbar[b * 64 + s] = sum * (1.0f / (NMEM * 8.0f));
}

// ---------------- s_pooled[b,n] = sum_s XKr[b, n*64+s] * qbar[b,s] -> bf16 ----------------
__global__ void spool_kernel(const ushort* __restrict__ XKr, const float* __restrict__ qbar,
                             ushort* __restrict__ spb) {
    int b = blockIdx.x;
    int n = threadIdx.x;  // 256 threads
    __shared__ float q[64];
    if (threadIdx.x < 64) q[threadIdx.x] = qbar[b * 64 + threadIdx.x];
    __syncthreads();
    const ushort* p = XKr + (size_t)b * NQK + n * 64;
    float sum = 0.0f;
    #pragma unroll
    for (int s = 0; s < 64; s += 4) {
        ushort4 u = *(const ushort4*)(p + s);
        sum += bf2f(u.x) * q[s] + bf2f(u.y) * q[s + 1]
             + bf2f(u.z) * q[s + 2] + bf2f(u.w) * q[s + 3];
    }
    spb[b * 256 + n] = f2bf(sum);
}

extern "C" void kernel_launch(void* const* d_in, const int* in_sizes, int n_in,
                              void* d_out, int out_size, void* d_ws, size_t ws_size,
                              hipStream_t stream) {
    const float* x  = (const float*)d_in[0];
    const float* Wq = (const float*)d_in[1];
    const float* bq = (const float*)d_in[2];
    const float* Wk = (const float*)d_in[3];
    const float* bk = (const float*)d_in[4];
    const float* v  = (const float*)d_in[5];
    const float* Wl = (const float*)d_in[6];
    const float* bl = (const float*)d_in[7];
    float* out = (float*)d_out;

    const size_t MB = 1ull << 20;
    char* ws = (char*)d_ws;
    ushort* xb   = (ushort*)(ws + 0);        //  8 MB  x bf16 [1024][4096]
    ushort* XQr  = (ushort*)(ws + 8 * MB);   // 32 MB  relu(x@Wq+bq) bf16 [1024][16384]
    ushort* XKr  = (ushort*)(ws + 40 * MB);  // 32 MB
    float*  qbar = (float*)(ws + 72 * MB);   // 256 KB [1024][64]
    ushort* spb  = (ushort*)(ws + 73 * MB);  // 512 KB s_pooled bf16 [1024][256]
    ushort* p2b  = (ushort*)(ws + 74 * MB);  //  8 MB  (spb@v) bf16 [1024][4096]
    ushort* WT   = (ushort*)(ws + 82 * MB);  // 128 MB transposed bf16 weight [16384][4096]

    // x -> bf16
    cvt_kernel<<<dim3((B_SZ * FIN) / 8 / 256), 256, 0, stream>>>(x, xb, B_SZ * FIN);

    // Q projection: full-N transpose (128 MB WT), one 256^2 GEMM (grid 64x4 = 256 blocks)
    transT_kernel<<<dim3(NQK / 64, FIN / 64), 256, 0, stream>>>(Wq, WT, NQK, 0);
    gemm256<1, 1><<<dim3(NQK / 256, B_SZ / 256), 512, 0, stream>>>(
        xb, WT, bq, XQr, NQK, FIN);
    qbar_kernel<<<dim3(B_SZ), 64, 0, stream>>>(XQr, qbar);

    // K projection
    transT_kernel<<<dim3(NQK / 64, FIN / 64), 256, 0, stream>>>(Wk, WT, NQK, 0);
    gemm256<1, 1><<<dim3(NQK / 256, B_SZ / 256), 512, 0, stream>>>(
        xb, WT, bk, XKr, NQK, FIN);
    spool_kernel<<<dim3(B_SZ), 256, 0, stream>>>(XKr, qbar, spb);

    // p2 = spb @ v  (fp32-B path, K=256), bf16 out
    gemm_k<0, 0, 0, 1><<<dim3(FIN / BN, B_SZ / BM), 256, 0, stream>>>(
        spb, v, nullptr, nullptr, p2b, B_SZ, FIN, NMEM);

    // WlT (32 MB into WT buffer), then out = x + p2 @ Wl + bl
    transT_kernel<<<dim3(FIN / 64, FIN / 64), 256, 0, stream>>>(Wl, WT, FIN, 0);
    gemm_bf<0, 1, 1, 0><<<dim3(FIN / 128, B_SZ / 128), 256, 0, stream>>>(
        p2b, WT, bl, x, out, FIN, B_SZ, FIN);
}